// Round 6
// baseline (261.650 us; speedup 1.0000x reference)
//
#include <hip/hip_runtime.h>
#include <hip/hip_bf16.h>

#define BATCH 4
#define SEQ   2048
#define EMB   1024
#define NH    16
#define HD    64

// workspace bf16-element offsets (total 28,311,552 elems = 56.6 MB)
#define Q_OFF  ((size_t)0)           // q  [B][H][T][D]  (0.125*log2e folded into Wq)
#define K_OFF  ((size_t)8388608)     // k  [B][H][T][D]
#define V_OFF  ((size_t)16777216)    // vT [B][H][D][T]
#define WT_OFF ((size_t)25165824)    // Wt [3072][1024] = [mh*64+d][e]

typedef __attribute__((ext_vector_type(8))) short short8;   // 8 bf16
typedef __attribute__((ext_vector_type(4))) short short4v;  // 4 bf16 (8B)
typedef __attribute__((ext_vector_type(4))) float f32x4;    // MFMA acc

__device__ __forceinline__ short8 pack8s(float4 a, float4 b, float s) {
    alignas(16) __hip_bfloat16 t[8] = {
        __float2bfloat16(a.x * s), __float2bfloat16(a.y * s),
        __float2bfloat16(a.z * s), __float2bfloat16(a.w * s),
        __float2bfloat16(b.x * s), __float2bfloat16(b.y * s),
        __float2bfloat16(b.z * s), __float2bfloat16(b.w * s)};
    return *reinterpret_cast<const short8*>(t);
}

// async global->LDS, 16B per lane. LDS dest is wave-uniform base + lane*16.
__device__ __forceinline__ void async16(void* lds, const void* g) {
    __builtin_amdgcn_global_load_lds(
        (const __attribute__((address_space(1))) unsigned int*)g,
        (__attribute__((address_space(3))) unsigned int*)lds, 16, 0, 0);
}

// ---------------------------------------------------------------------------
// Kernel A: x fp32 -> bf16 (linear). Output lives in d_out (overwritten later).
// ---------------------------------------------------------------------------
__global__ __launch_bounds__(256)
void xcast_kernel(const float* __restrict__ x, __hip_bfloat16* __restrict__ xb)
{
    const size_t i = ((size_t)blockIdx.x * 256 + threadIdx.x) * 8;
    float4 f0 = ((const float4*)(x + i))[0];
    float4 f1 = ((const float4*)(x + i))[1];
    *(short8*)(xb + i) = pack8s(f0, f1, 1.0f);
}

// ---------------------------------------------------------------------------
// Kernel B: W transpose+cast: W[h][e][d] fp32 -> Wt[mh*64+d][e] bf16.
// Wq rows scaled by 0.125*log2(e): attention softmax runs in log2 domain.
// ---------------------------------------------------------------------------
__global__ __launch_bounds__(256)
void wt_kernel(const float* __restrict__ Wq, const float* __restrict__ Wk,
               const float* __restrict__ Wv, __hip_bfloat16* __restrict__ Wt)
{
    const int et = blockIdx.x;               // 16 e-tiles of 64
    const int mh = blockIdx.y;               // 48
    const int m = mh >> 4, h = mh & 15;
    const float* W = ((m == 0) ? Wq : (m == 1) ? Wk : Wv) + (size_t)h * (EMB * HD);
    const float scale = (m == 0) ? 0.18033688011112042f : 1.0f;  // 0.125*log2(e)

    __shared__ __hip_bfloat16 T[64][72];     // [d][e-local]
    const int tid = threadIdx.x;
    const int r   = tid >> 2;                // 0..63
    const int seg = (tid & 3) * 16;

    {
        const float* src = W + (size_t)(et * 64 + r) * HD + seg;
        float4 f0 = ((const float4*)src)[0];
        float4 f1 = ((const float4*)src)[1];
        float4 f2 = ((const float4*)src)[2];
        float4 f3 = ((const float4*)src)[3];
        const float v[16] = {f0.x,f0.y,f0.z,f0.w, f1.x,f1.y,f1.z,f1.w,
                             f2.x,f2.y,f2.z,f2.w, f3.x,f3.y,f3.z,f3.w};
        #pragma unroll
        for (int j = 0; j < 16; ++j) T[seg + j][r] = __float2bfloat16(v[j] * scale);
    }
    __syncthreads();
    __hip_bfloat16* dst = Wt + ((size_t)mh * HD + r) * EMB + et * 64 + seg;
    *(short8*)dst       = *(const short8*)&T[r][seg];
    *(short8*)(dst + 8) = *(const short8*)&T[r][seg + 8];
}

// ---------------------------------------------------------------------------
// Kernel 1: QKV projection as bf16 GEMM (m97 structure) — unchanged.
// ---------------------------------------------------------------------------
__global__ __launch_bounds__(256)
void qkv_proj_kernel(const __hip_bfloat16* __restrict__ xb,   // [8192][1024]
                     const __hip_bfloat16* __restrict__ Wt,   // [3072][1024]
                     __hip_bfloat16* __restrict__ qkv)
{
    const int nt = blockIdx.x;               // 0..23 col tiles (2 heads each)
    const int rt = blockIdx.y;               // 0..63 row tiles
    const int row0 = rt * 128;
    const int n0   = nt * 128;

    __shared__ __hip_bfloat16 lds[17408];
    __hip_bfloat16* As = lds;                // [128][64] swizzled, row=128B
    __hip_bfloat16* Bs = lds + 8192;         // [128][64] swizzled

    const int tid  = threadIdx.x;
    const int wave = tid >> 6;
    const int lane = tid & 63;
    const int lr   = lane & 15;
    const int lg   = lane >> 4;

    const int srow  = lane >> 3;
    const int sslot = (lane & 7) ^ srow;
    const char* aSrc = (const char*)xb + (size_t)(row0 + wave * 32 + srow) * 2048 + sslot * 16;
    const char* bSrc = (const char*)Wt + (size_t)(n0   + wave * 32 + srow) * 2048 + sslot * 16;
    char* aDst = (char*)As + (size_t)(wave * 32) * 128;
    char* bDst = (char*)Bs + (size_t)(wave * 32) * 128;

    f32x4 acc[2][8] = {};

    for (int k0 = 0; k0 < EMB; k0 += 64) {
        __syncthreads();
        #pragma unroll
        for (int i = 0; i < 4; ++i) {
            async16(aDst + i * 1024, aSrc + (size_t)i * 16384 + k0 * 2);
            async16(bDst + i * 1024, bSrc + (size_t)i * 16384 + k0 * 2);
        }
        __syncthreads();

        #pragma unroll
        for (int half = 0; half < 2; ++half) {
            const int cg = half * 4 + lg;
            const int r0a = wave * 32 + lr;
            const int r1a = wave * 32 + 16 + lr;
            short8 a0 = *(const short8*)((char*)As + r0a * 128 + ((cg ^ (r0a & 7)) * 16));
            short8 a1 = *(const short8*)((char*)As + r1a * 128 + ((cg ^ (r1a & 7)) * 16));
            #pragma unroll
            for (int ct = 0; ct < 8; ++ct) {
                const int rb = ct * 16 + lr;
                short8 bf = *(const short8*)((char*)Bs + rb * 128 + ((cg ^ (rb & 7)) * 16));
                acc[0][ct] = __builtin_amdgcn_mfma_f32_16x16x32_bf16(a0, bf, acc[0][ct], 0, 0, 0);
                acc[1][ct] = __builtin_amdgcn_mfma_f32_16x16x32_bf16(a1, bf, acc[1][ct], 0, 0, 0);
            }
        }
    }

    const int m   = n0 >> 10;                 // 0,1,2
    const int b   = row0 >> 11;
    const int tl0 = (row0 & (SEQ - 1)) + wave * 32;
    if (m < 2) {
        __hip_bfloat16* outp = qkv + ((m == 0) ? Q_OFF : K_OFF)
                             + (size_t)b * NH * SEQ * HD;
        #pragma unroll
        for (int rsub = 0; rsub < 2; ++rsub)
            #pragma unroll
            for (int ct = 0; ct < 8; ++ct) {
                const int h = (2 * nt + (ct >> 2)) & 15;
                const int d = (ct & 3) * 16 + lr;
                #pragma unroll
                for (int i = 0; i < 4; ++i) {
                    const int trow = tl0 + rsub * 16 + lg * 4 + i;
                    outp[((size_t)h * SEQ + trow) * HD + d] = __float2bfloat16(acc[rsub][ct][i]);
                }
            }
    } else {
        __hip_bfloat16 (*Ts)[136] = (__hip_bfloat16(*)[136])lds;
        __syncthreads();
        #pragma unroll
        for (int rsub = 0; rsub < 2; ++rsub)
            #pragma unroll
            for (int ct = 0; ct < 8; ++ct)
                #pragma unroll
                for (int i = 0; i < 4; ++i)
                    Ts[ct * 16 + lr][wave * 32 + rsub * 16 + lg * 4 + i] =
                        __float2bfloat16(acc[rsub][ct][i]);
        __syncthreads();
        const int c    = tid >> 1;
        const int tseg = (tid & 1) * 64;
        const int hv   = (2 * nt + (c >> 6)) & 15;
        const int dv   = c & 63;
        __hip_bfloat16* dst = qkv + V_OFF + ((size_t)b * NH + hv) * (HD * SEQ)
                            + (size_t)dv * SEQ + (row0 & (SEQ - 1)) + tseg;
        #pragma unroll
        for (int q = 0; q < 8; ++q)
            *(short8*)(dst + q * 8) = *(const short8*)&Ts[c][tseg + q * 8];
    }
}

// ---------------------------------------------------------------------------
// Kernel 2: causal flash attention, swapped-operand (S^T / O^T), BARRIER-FREE.
// K/V fragments load directly from global (L1/L2-resident tiles) — no K/V
// LDS staging, no __syncthreads in the K-loop; waves free-run with setprio.
// 1024 blocks (one 128-row q-tile each), longest-first per XCD chunk.
// ---------------------------------------------------------------------------
__global__ __launch_bounds__(256)
void attn_kernel(const __hip_bfloat16* __restrict__ ws, float* __restrict__ out)
{
    const int bid     = blockIdx.x;                  // 1024
    const int logical = (bid & 7) * 128 + (bid >> 3);// XCD chunk: 8 bh per XCD (4MB=L2)
    const int qt = 15 - (logical & 15);              // longest blocks dispatch first
    const int bh = logical >> 4;
    const int h  = bh & 15;
    const int b  = bh >> 4;
    const int qbase = qt * 128;
    const int ktmax = 2 * qt + 1;

    const __hip_bfloat16* qp = ws + Q_OFF + (size_t)bh * (SEQ * HD);
    const __hip_bfloat16* kp = ws + K_OFF + (size_t)bh * (SEQ * HD);
    const __hip_bfloat16* vt = ws + V_OFF + (size_t)bh * (HD * SEQ);  // [d][t]

    // P buffer only: per-wave, per-rsub, swizzled rows of 128B
    __shared__ __align__(16) __hip_bfloat16 Psb[4][2][1024];   // 16 KB

    const int tid  = threadIdx.x;
    const int wave = tid >> 6;
    const int lane = tid & 63;
    const int lr   = lane & 15;
    const int lg   = lane >> 4;
    const int l7   = lr & 7;

    // Q fragments (B-operand layout; 0.125*log2e folded in at projection)
    short8 qf[2][2];
    #pragma unroll
    for (int rsub = 0; rsub < 2; ++rsub) {
        const __hip_bfloat16* src =
            qp + (size_t)(qbase + wave * 32 + rsub * 16 + lr) * HD + lg * 8;
        qf[rsub][0] = *(const short8*)src;
        qf[rsub][1] = *(const short8*)(src + 32);
    }

    float m_run[2] = {-1e30f, -1e30f};
    float l_run[2] = {0.f, 0.f};
    f32x4 o_acc[2][4] = {};

    // per-lane fragment offsets (constant across tiles)
    const __hip_bfloat16* kfp = kp + (size_t)(lr) * HD + lg * 8;   // + ct*16*HD + {0,32}
    const __hip_bfloat16* vfp = vt + (size_t)(lr) * SEQ + lg * 8;  // + ct*16*SEQ + {0,32}

    for (int kt = 0; kt <= ktmax; ++kt) {
        const int kbase = kt * 64;

        // --- K fragments: 8 x 16B direct global loads (L1/L2 hits) ---
        short8 kf[4][2];
        #pragma unroll
        for (int ct = 0; ct < 4; ++ct) {
            const __hip_bfloat16* kb = kfp + (size_t)(kbase + ct * 16) * HD;
            kf[ct][0] = *(const short8*)kb;
            kf[ct][1] = *(const short8*)(kb + 32);
        }

        // --- S^T = K . Q^T ---
        f32x4 s[2][4];
        __builtin_amdgcn_s_setprio(1);
        #pragma unroll
        for (int ct = 0; ct < 4; ++ct)
            #pragma unroll
            for (int rsub = 0; rsub < 2; ++rsub) {
                f32x4 z = {};
                z           = __builtin_amdgcn_mfma_f32_16x16x32_bf16(kf[ct][0], qf[rsub][0], z, 0, 0, 0);
                s[rsub][ct] = __builtin_amdgcn_mfma_f32_16x16x32_bf16(kf[ct][1], qf[rsub][1], z, 0, 0, 0);
            }
        __builtin_amdgcn_s_setprio(0);

        // --- V fragments: issue now, consumed after softmax (latency hidden) ---
        short8 vf[4][2];
        #pragma unroll
        for (int ct = 0; ct < 4; ++ct) {
            const __hip_bfloat16* vb = vfp + (size_t)(ct * 16) * SEQ + kbase;
            vf[ct][0] = *(const short8*)vb;
            vf[ct][1] = *(const short8*)(vb + 32);
        }

        if (kt >= 2 * qt) {   // causal mask (diagonal region only)
            #pragma unroll
            for (int rsub = 0; rsub < 2; ++rsub) {
                const int qrow = qbase + wave * 32 + rsub * 16 + lr;
                #pragma unroll
                for (int ct = 0; ct < 4; ++ct)
                    #pragma unroll
                    for (int i = 0; i < 4; ++i) {
                        const int key = kbase + ct * 16 + lg * 4 + i;
                        s[rsub][ct][i] = (key > qrow) ? -1e30f : s[rsub][ct][i];
                    }
            }
        }

        // --- softmax (log2 domain, defer-max), both rsub, P -> LDS ---
        #pragma unroll
        for (int rsub = 0; rsub < 2; ++rsub) {
            float pmax = fmaxf(
                fmaxf(fmaxf(fmaxf(s[rsub][0][0], s[rsub][0][1]), fmaxf(s[rsub][0][2], s[rsub][0][3])),
                      fmaxf(fmaxf(s[rsub][1][0], s[rsub][1][1]), fmaxf(s[rsub][1][2], s[rsub][1][3]))),
                fmaxf(fmaxf(fmaxf(s[rsub][2][0], s[rsub][2][1]), fmaxf(s[rsub][2][2], s[rsub][2][3])),
                      fmaxf(fmaxf(s[rsub][3][0], s[rsub][3][1]), fmaxf(s[rsub][3][2], s[rsub][3][3]))));
            pmax = fmaxf(pmax, __shfl_xor(pmax, 16, 64));
            pmax = fmaxf(pmax, __shfl_xor(pmax, 32, 64));

            if (__any(pmax > m_run[rsub] + 8.0f)) {   // T13 defer-max, P <= 256
                const float mnew = fmaxf(m_run[rsub], pmax);
                const float corr = __builtin_amdgcn_exp2f(m_run[rsub] - mnew);
                l_run[rsub] *= corr;
                #pragma unroll
                for (int ct = 0; ct < 4; ++ct)
                    #pragma unroll
                    for (int i = 0; i < 4; ++i)
                        o_acc[rsub][ct][i] *= corr;
                m_run[rsub] = mnew;
            }

            const float mcur = m_run[rsub];
            float rs0 = 0.f, rs1 = 0.f;
            #pragma unroll
            for (int ct = 0; ct < 4; ++ct) {
                const float p0 = __builtin_amdgcn_exp2f(s[rsub][ct][0] - mcur);
                const float p1 = __builtin_amdgcn_exp2f(s[rsub][ct][1] - mcur);
                const float p2 = __builtin_amdgcn_exp2f(s[rsub][ct][2] - mcur);
                const float p3 = __builtin_amdgcn_exp2f(s[rsub][ct][3] - mcur);
                rs0 += p0 + p1;
                rs1 += p2 + p3;
                alignas(8) __hip_bfloat16 t[4] = {
                    __float2bfloat16(p0), __float2bfloat16(p1),
                    __float2bfloat16(p2), __float2bfloat16(p3)};
                *(short4v*)((char*)Psb[wave][rsub] + lr * 128
                    + (((2 * ct + (lg >> 1)) ^ l7) << 4) + 8 * (lg & 1)) = *(const short4v*)t;
            }
            float rs = rs0 + rs1;
            rs += __shfl_xor(rs, 16, 64);
            rs += __shfl_xor(rs, 32, 64);
            l_run[rsub] += rs;
        }

        // --- O^T += V^T . P^T (vf in regs, pf from per-wave LDS) ---
        short8 pf[2][2];
        #pragma unroll
        for (int rsub = 0; rsub < 2; ++rsub) {
            const char* pb = (const char*)Psb[wave][rsub] + lr * 128;
            pf[rsub][0] = *(const short8*)(pb + ((lg      ^ l7) << 4));
            pf[rsub][1] = *(const short8*)(pb + (((lg + 4) ^ l7) << 4));
        }
        __builtin_amdgcn_s_setprio(1);
        #pragma unroll
        for (int ct = 0; ct < 4; ++ct)
            #pragma unroll
            for (int rsub = 0; rsub < 2; ++rsub) {
                o_acc[rsub][ct] = __builtin_amdgcn_mfma_f32_16x16x32_bf16(vf[ct][0], pf[rsub][0], o_acc[rsub][ct], 0, 0, 0);
                o_acc[rsub][ct] = __builtin_amdgcn_mfma_f32_16x16x32_bf16(vf[ct][1], pf[rsub][1], o_acc[rsub][ct], 0, 0, 0);
            }
        __builtin_amdgcn_s_setprio(0);
    }

    // epilogue: O^T -> out[b][t][h*64+d]; qrow lane-local -> float4 stores
    float* op = out + (size_t)b * SEQ * (NH * HD) + (size_t)h * HD;
    #pragma unroll
    for (int rsub = 0; rsub < 2; ++rsub) {
        const float inv  = 1.0f / l_run[rsub];
        const int   trow = qbase + wave * 32 + rsub * 16 + lr;
        #pragma unroll
        for (int ct = 0; ct < 4; ++ct) {
            float4 o;
            o.x = o_acc[rsub][ct][0] * inv;
            o.y = o_acc[rsub][ct][1] * inv;
            o.z = o_acc[rsub][ct][2] * inv;
            o.w = o_acc[rsub][ct][3] * inv;
            *(float4*)&op[(size_t)trow * (NH * HD) + ct * 16 + lg * 4] = o;
        }
    }
}

extern "C" void kernel_launch(void* const* d_in, const int* in_sizes, int n_in,
                              void* d_out, int out_size, void* d_ws, size_t ws_size,
                              hipStream_t stream) {
    const float* x  = (const float*)d_in[0];
    const float* Wq = (const float*)d_in[1];
    const float* Wk = (const float*)d_in[2];
    const float* Wv = (const float*)d_in[3];
    float* out = (float*)d_out;
    __hip_bfloat16* ws = (__hip_bfloat16*)d_ws;

    __hip_bfloat16* xb = (__hip_bfloat16*)d_out;   // overwritten by attn later

    hipLaunchKernelGGL(xcast_kernel, dim3((BATCH * SEQ * EMB) / (256 * 8)), dim3(256),
                       0, stream, x, xb);
    hipLaunchKernelGGL(wt_kernel, dim3(16, 48), dim3(256), 0, stream,
                       Wq, Wk, Wv, ws + WT_OFF);
    hipLaunchKernelGGL(qkv_proj_kernel, dim3(24, 64), dim3(256), 0, stream,
                       xb, ws + WT_OFF, ws);
    hipLaunchKernelGGL(attn_kernel, dim3(1024), dim3(256), 0, stream, ws, out);
}

// Round 7
// 182.806 us; speedup vs baseline: 1.4313x; 1.4313x over previous
//
#include <hip/hip_runtime.h>
#include <hip/hip_bf16.h>

#define BATCH 4
#define SEQ   2048
#define EMB   1024
#define NH    16
#define HD    64

// workspace bf16-element offsets (total 28,311,552 elems = 56.6 MB)
#define Q_OFF  ((size_t)0)           // q  [B][H][T][D]  (0.125*log2e folded into Wq)
#define K_OFF  ((size_t)8388608)     // k  [B][H][T][D]
#define V_OFF  ((size_t)16777216)    // vT [B][H][D][T]
#define WT_OFF ((size_t)25165824)    // Wt [3072][1024] = [mh*64+d][e]

typedef __attribute__((ext_vector_type(8))) short short8;   // 8 bf16
typedef __attribute__((ext_vector_type(4))) short short4v;  // 4 bf16 (8B)
typedef __attribute__((ext_vector_type(4))) float f32x4;    // MFMA acc

__device__ __forceinline__ short8 pack8s(float4 a, float4 b, float s) {
    alignas(16) __hip_bfloat16 t[8] = {
        __float2bfloat16(a.x * s), __float2bfloat16(a.y * s),
        __float2bfloat16(a.z * s), __float2bfloat16(a.w * s),
        __float2bfloat16(b.x * s), __float2bfloat16(b.y * s),
        __float2bfloat16(b.z * s), __float2bfloat16(b.w * s)};
    return *reinterpret_cast<const short8*>(t);
}

// async global->LDS, 16B per lane. LDS dest is wave-uniform base + lane*16.
__device__ __forceinline__ void async16(void* lds, const void* g) {
    __builtin_amdgcn_global_load_lds(
        (const __attribute__((address_space(1))) unsigned int*)g,
        (__attribute__((address_space(3))) unsigned int*)lds, 16, 0, 0);
}

// ---------------------------------------------------------------------------
// Kernel A: x fp32 -> bf16 (linear). Output lives in d_out (overwritten later).
// ---------------------------------------------------------------------------
__global__ __launch_bounds__(256)
void xcast_kernel(const float* __restrict__ x, __hip_bfloat16* __restrict__ xb)
{
    const size_t i = ((size_t)blockIdx.x * 256 + threadIdx.x) * 8;
    float4 f0 = ((const float4*)(x + i))[0];
    float4 f1 = ((const float4*)(x + i))[1];
    *(short8*)(xb + i) = pack8s(f0, f1, 1.0f);
}

// ---------------------------------------------------------------------------
// Kernel B: W transpose+cast: W[h][e][d] fp32 -> Wt[mh*64+d][e] bf16.
// Wq rows scaled by 0.125*log2(e): attention softmax runs in log2 domain.
// ---------------------------------------------------------------------------
__global__ __launch_bounds__(256)
void wt_kernel(const float* __restrict__ Wq, const float* __restrict__ Wk,
               const float* __restrict__ Wv, __hip_bfloat16* __restrict__ Wt)
{
    const int et = blockIdx.x;               // 16 e-tiles of 64
    const int mh = blockIdx.y;               // 48
    const int m = mh >> 4, h = mh & 15;
    const float* W = ((m == 0) ? Wq : (m == 1) ? Wk : Wv) + (size_t)h * (EMB * HD);
    const float scale = (m == 0) ? 0.18033688011112042f : 1.0f;  // 0.125*log2(e)

    __shared__ __hip_bfloat16 T[64][72];     // [d][e-local]
    const int tid = threadIdx.x;
    const int r   = tid >> 2;                // 0..63
    const int seg = (tid & 3) * 16;

    {
        const float* src = W + (size_t)(et * 64 + r) * HD + seg;
        float4 f0 = ((const float4*)src)[0];
        float4 f1 = ((const float4*)src)[1];
        float4 f2 = ((const float4*)src)[2];
        float4 f3 = ((const float4*)src)[3];
        const float v[16] = {f0.x,f0.y,f0.z,f0.w, f1.x,f1.y,f1.z,f1.w,
                             f2.x,f2.y,f2.z,f2.w, f3.x,f3.y,f3.z,f3.w};
        #pragma unroll
        for (int j = 0; j < 16; ++j) T[seg + j][r] = __float2bfloat16(v[j] * scale);
    }
    __syncthreads();
    __hip_bfloat16* dst = Wt + ((size_t)mh * HD + r) * EMB + et * 64 + seg;
    *(short8*)dst       = *(const short8*)&T[r][seg];
    *(short8*)(dst + 8) = *(const short8*)&T[r][seg + 8];
}

// ---------------------------------------------------------------------------
// Kernel 1: QKV projection as bf16 GEMM (m97 structure) — unchanged.
// ---------------------------------------------------------------------------
__global__ __launch_bounds__(256)
void qkv_proj_kernel(const __hip_bfloat16* __restrict__ xb,   // [8192][1024]
                     const __hip_bfloat16* __restrict__ Wt,   // [3072][1024]
                     __hip_bfloat16* __restrict__ qkv)
{
    const int nt = blockIdx.x;               // 0..23 col tiles (2 heads each)
    const int rt = blockIdx.y;               // 0..63 row tiles
    const int row0 = rt * 128;
    const int n0   = nt * 128;

    __shared__ __hip_bfloat16 lds[17408];
    __hip_bfloat16* As = lds;                // [128][64] swizzled, row=128B
    __hip_bfloat16* Bs = lds + 8192;         // [128][64] swizzled

    const int tid  = threadIdx.x;
    const int wave = tid >> 6;
    const int lane = tid & 63;
    const int lr   = lane & 15;
    const int lg   = lane >> 4;

    const int srow  = lane >> 3;
    const int sslot = (lane & 7) ^ srow;
    const char* aSrc = (const char*)xb + (size_t)(row0 + wave * 32 + srow) * 2048 + sslot * 16;
    const char* bSrc = (const char*)Wt + (size_t)(n0   + wave * 32 + srow) * 2048 + sslot * 16;
    char* aDst = (char*)As + (size_t)(wave * 32) * 128;
    char* bDst = (char*)Bs + (size_t)(wave * 32) * 128;

    f32x4 acc[2][8] = {};

    for (int k0 = 0; k0 < EMB; k0 += 64) {
        __syncthreads();
        #pragma unroll
        for (int i = 0; i < 4; ++i) {
            async16(aDst + i * 1024, aSrc + (size_t)i * 16384 + k0 * 2);
            async16(bDst + i * 1024, bSrc + (size_t)i * 16384 + k0 * 2);
        }
        __syncthreads();

        #pragma unroll
        for (int half = 0; half < 2; ++half) {
            const int cg = half * 4 + lg;
            const int r0a = wave * 32 + lr;
            const int r1a = wave * 32 + 16 + lr;
            short8 a0 = *(const short8*)((char*)As + r0a * 128 + ((cg ^ (r0a & 7)) * 16));
            short8 a1 = *(const short8*)((char*)As + r1a * 128 + ((cg ^ (r1a & 7)) * 16));
            #pragma unroll
            for (int ct = 0; ct < 8; ++ct) {
                const int rb = ct * 16 + lr;
                short8 bf = *(const short8*)((char*)Bs + rb * 128 + ((cg ^ (rb & 7)) * 16));
                acc[0][ct] = __builtin_amdgcn_mfma_f32_16x16x32_bf16(a0, bf, acc[0][ct], 0, 0, 0);
                acc[1][ct] = __builtin_amdgcn_mfma_f32_16x16x32_bf16(a1, bf, acc[1][ct], 0, 0, 0);
            }
        }
    }

    const int m   = n0 >> 10;                 // 0,1,2
    const int b   = row0 >> 11;
    const int tl0 = (row0 & (SEQ - 1)) + wave * 32;
    if (m < 2) {
        __hip_bfloat16* outp = qkv + ((m == 0) ? Q_OFF : K_OFF)
                             + (size_t)b * NH * SEQ * HD;
        #pragma unroll
        for (int rsub = 0; rsub < 2; ++rsub)
            #pragma unroll
            for (int ct = 0; ct < 8; ++ct) {
                const int h = (2 * nt + (ct >> 2)) & 15;
                const int d = (ct & 3) * 16 + lr;
                #pragma unroll
                for (int i = 0; i < 4; ++i) {
                    const int trow = tl0 + rsub * 16 + lg * 4 + i;
                    outp[((size_t)h * SEQ + trow) * HD + d] = __float2bfloat16(acc[rsub][ct][i]);
                }
            }
    } else {
        __hip_bfloat16 (*Ts)[136] = (__hip_bfloat16(*)[136])lds;
        __syncthreads();
        #pragma unroll
        for (int rsub = 0; rsub < 2; ++rsub)
            #pragma unroll
            for (int ct = 0; ct < 8; ++ct)
                #pragma unroll
                for (int i = 0; i < 4; ++i)
                    Ts[ct * 16 + lr][wave * 32 + rsub * 16 + lg * 4 + i] =
                        __float2bfloat16(acc[rsub][ct][i]);
        __syncthreads();
        const int c    = tid >> 1;
        const int tseg = (tid & 1) * 64;
        const int hv   = (2 * nt + (c >> 6)) & 15;
        const int dv   = c & 63;
        __hip_bfloat16* dst = qkv + V_OFF + ((size_t)b * NH + hv) * (HD * SEQ)
                            + (size_t)dv * SEQ + (row0 & (SEQ - 1)) + tseg;
        #pragma unroll
        for (int q = 0; q < 8; ++q)
            *(short8*)(dst + q * 8) = *(const short8*)&Ts[c][tseg + q * 8];
    }
}

// ---------------------------------------------------------------------------
// Kernel 2: causal flash attention, swapped-operand (S^T / O^T), r5 structure.
// UNPAIRED: 1024 blocks, one 128-row q-tile each -> 4 blocks/CU (LDS 40KB).
// Longest-first within XCD chunks; dbuf gload_lds staging; 1 barrier/tile.
// ---------------------------------------------------------------------------
__global__ __launch_bounds__(256)
void attn_kernel(const __hip_bfloat16* __restrict__ ws, float* __restrict__ out)
{
    const int bid     = blockIdx.x;                  // 1024
    const int logical = (bid & 7) * 128 + (bid >> 3);// XCD chunk: 8 bh per XCD (4MB=L2)
    const int qt = 15 - (logical & 15);              // longest q-tiles dispatch first
    const int bh = logical >> 4;
    const int h  = bh & 15;
    const int b  = bh >> 4;
    const int qbase = qt * 128;
    const int ktmax = 2 * qt + 1;

    const __hip_bfloat16* qp = ws + Q_OFF + (size_t)bh * (SEQ * HD);
    const __hip_bfloat16* kp = ws + K_OFF + (size_t)bh * (SEQ * HD);
    const __hip_bfloat16* vt = ws + V_OFF + (size_t)bh * (HD * SEQ);  // [d][t]

    // swizzled tiles: element slot s of row r at byte r*128 + ((s^(r&7))<<4)
    __shared__ __align__(16) __hip_bfloat16 Ksb[2][4096];   // [buf][64 key][64 d]
    __shared__ __align__(16) __hip_bfloat16 Vsb[2][4096];   // [buf][64 d][64 key]
    __shared__ __align__(16) __hip_bfloat16 Psb[4][2][1024];// per-wave/rsub P

    const int tid  = threadIdx.x;
    const int wave = tid >> 6;
    const int lane = tid & 63;
    const int lr   = lane & 15;
    const int lg   = lane >> 4;
    const int l7   = lr & 7;

    const int srow8 = lane >> 3;            // 0..7 within an 8-row issue
    const int sslot = (lane & 7) ^ srow8;   // source pre-swizzle slot

    // Q fragments (B-operand layout; 0.125*log2e folded in at projection)
    short8 qf[2][2];
    #pragma unroll
    for (int rsub = 0; rsub < 2; ++rsub) {
        const __hip_bfloat16* src =
            qp + (size_t)(qbase + wave * 32 + rsub * 16 + lr) * HD + lg * 8;
        qf[rsub][0] = *(const short8*)src;
        qf[rsub][1] = *(const short8*)(src + 32);
    }

    float m_run[2] = {-1e30f, -1e30f};
    float l_run[2] = {0.f, 0.f};
    f32x4 o_acc[2][4] = {};

    // async stage of one kv-tile into buf (each wave: 16 K rows + 16 V rows)
    auto stage = [&](int buf, int kbase) {
        #pragma unroll
        for (int j = 0; j < 2; ++j) {
            const int r0 = wave * 16 + j * 8;   // tile-local row base (mult of 8)
            async16((char*)Ksb[buf] + r0 * 128,
                    (const char*)(kp + (size_t)(kbase + r0 + srow8) * HD) + sslot * 16);
            async16((char*)Vsb[buf] + r0 * 128,
                    (const char*)(vt + (size_t)(r0 + srow8) * SEQ + kbase) + sslot * 16);
        }
    };

    stage(0, 0);
    __syncthreads();   // drains async: tile 0 resident

    for (int kt = 0; kt <= ktmax; ++kt) {
        const int cur = kt & 1;
        if (kt < ktmax) stage(cur ^ 1, (kt + 1) * 64);   // T14: issue early

        // S^T = K . Q^T : s[rsub][ct][i] = S[key=ct*16+lg*4+i][qrow(lr)]
        f32x4 s[2][4];
        __builtin_amdgcn_s_setprio(1);
        #pragma unroll
        for (int ct = 0; ct < 4; ++ct) {
            const char* kb = (const char*)Ksb[cur] + (ct * 16 + lr) * 128;
            short8 kf0 = *(const short8*)(kb + ((lg      ^ l7) << 4));
            short8 kf1 = *(const short8*)(kb + (((lg + 4) ^ l7) << 4));
            #pragma unroll
            for (int rsub = 0; rsub < 2; ++rsub) {
                f32x4 z = {};
                z           = __builtin_amdgcn_mfma_f32_16x16x32_bf16(kf0, qf[rsub][0], z, 0, 0, 0);
                s[rsub][ct] = __builtin_amdgcn_mfma_f32_16x16x32_bf16(kf1, qf[rsub][1], z, 0, 0, 0);
            }
        }
        __builtin_amdgcn_s_setprio(0);

        const int kbase = kt * 64;
        if (kt >= 2 * qt) {   // causal mask (diagonal tiles only)
            #pragma unroll
            for (int rsub = 0; rsub < 2; ++rsub) {
                const int qrow = qbase + wave * 32 + rsub * 16 + lr;
                #pragma unroll
                for (int ct = 0; ct < 4; ++ct)
                    #pragma unroll
                    for (int i = 0; i < 4; ++i) {
                        const int key = kbase + ct * 16 + lg * 4 + i;
                        s[rsub][ct][i] = (key > qrow) ? -1e30f : s[rsub][ct][i];
                    }
            }
        }

        #pragma unroll
        for (int rsub = 0; rsub < 2; ++rsub) {
            // tile max: in-lane tree + 2 cross-group shuffles
            float pmax = fmaxf(
                fmaxf(fmaxf(fmaxf(s[rsub][0][0], s[rsub][0][1]), fmaxf(s[rsub][0][2], s[rsub][0][3])),
                      fmaxf(fmaxf(s[rsub][1][0], s[rsub][1][1]), fmaxf(s[rsub][1][2], s[rsub][1][3]))),
                fmaxf(fmaxf(fmaxf(s[rsub][2][0], s[rsub][2][1]), fmaxf(s[rsub][2][2], s[rsub][2][3])),
                      fmaxf(fmaxf(s[rsub][3][0], s[rsub][3][1]), fmaxf(s[rsub][3][2], s[rsub][3][3]))));
            pmax = fmaxf(pmax, __shfl_xor(pmax, 16, 64));
            pmax = fmaxf(pmax, __shfl_xor(pmax, 32, 64));

            // T13 defer-max (log2 domain, THR=8 -> P <= 256)
            if (__any(pmax > m_run[rsub] + 8.0f)) {
                const float mnew = fmaxf(m_run[rsub], pmax);
                const float corr = __builtin_amdgcn_exp2f(m_run[rsub] - mnew);
                l_run[rsub] *= corr;
                #pragma unroll
                for (int ct = 0; ct < 4; ++ct)
                    #pragma unroll
                    for (int i = 0; i < 4; ++i)
                        o_acc[rsub][ct][i] *= corr;
                m_run[rsub] = mnew;
            }

            const float mcur = m_run[rsub];
            float rs0 = 0.f, rs1 = 0.f;
            #pragma unroll
            for (int ct = 0; ct < 4; ++ct) {
                const float p0 = __builtin_amdgcn_exp2f(s[rsub][ct][0] - mcur);
                const float p1 = __builtin_amdgcn_exp2f(s[rsub][ct][1] - mcur);
                const float p2 = __builtin_amdgcn_exp2f(s[rsub][ct][2] - mcur);
                const float p3 = __builtin_amdgcn_exp2f(s[rsub][ct][3] - mcur);
                rs0 += p0 + p1;
                rs1 += p2 + p3;
                alignas(8) __hip_bfloat16 t[4] = {
                    __float2bfloat16(p0), __float2bfloat16(p1),
                    __float2bfloat16(p2), __float2bfloat16(p3)};
                *(short4v*)((char*)Psb[wave][rsub] + lr * 128
                    + (((2 * ct + (lg >> 1)) ^ l7) << 4) + 8 * (lg & 1)) = *(const short4v*)t;
            }
            float rs = rs0 + rs1;
            rs += __shfl_xor(rs, 16, 64);
            rs += __shfl_xor(rs, 32, 64);
            l_run[rsub] += rs;
        }

        // P fragments (lane-local rows) and O^T accumulate
        short8 pf[2][2];
        #pragma unroll
        for (int rsub = 0; rsub < 2; ++rsub) {
            const char* pb = (const char*)Psb[wave][rsub] + lr * 128;
            pf[rsub][0] = *(const short8*)(pb + ((lg      ^ l7) << 4));
            pf[rsub][1] = *(const short8*)(pb + (((lg + 4) ^ l7) << 4));
        }
        __builtin_amdgcn_s_setprio(1);
        #pragma unroll
        for (int ct = 0; ct < 4; ++ct) {
            const char* vb = (const char*)Vsb[cur] + (ct * 16 + lr) * 128;
            short8 vf0 = *(const short8*)(vb + ((lg      ^ l7) << 4));
            short8 vf1 = *(const short8*)(vb + (((lg + 4) ^ l7) << 4));
            #pragma unroll
            for (int rsub = 0; rsub < 2; ++rsub) {
                o_acc[rsub][ct] = __builtin_amdgcn_mfma_f32_16x16x32_bf16(vf0, pf[rsub][0], o_acc[rsub][ct], 0, 0, 0);
                o_acc[rsub][ct] = __builtin_amdgcn_mfma_f32_16x16x32_bf16(vf1, pf[rsub][1], o_acc[rsub][ct], 0, 0, 0);
            }
        }
        __builtin_amdgcn_s_setprio(0);

        __syncthreads();   // single barrier: drains async stage, fences dbuf swap
    }

    // epilogue: O^T -> out[b][t][h*64+d]; qrow lane-local -> float4 stores
    float* op = out + (size_t)b * SEQ * (NH * HD) + (size_t)h * HD;
    #pragma unroll
    for (int rsub = 0; rsub < 2; ++rsub) {
        const float inv  = 1.0f / l_run[rsub];
        const int   trow = qbase + wave * 32 + rsub * 16 + lr;
        #pragma unroll
        for (int ct = 0; ct < 4; ++ct) {
            float4 o;
            o.x = o_acc[rsub][ct][0] * inv;
            o.y = o_acc[rsub][ct][1] * inv;
            o.z = o_acc[rsub][ct][2] * inv;
            o.w = o_acc[rsub][ct][3] * inv;
            *(float4*)&op[(size_t)trow * (NH * HD) + ct * 16 + lg * 4] = o;
        }
    }
}

extern "C" void kernel_launch(void* const* d_in, const int* in_sizes, int n_in,
                              void* d_out, int out_size, void* d_ws, size_t ws_size,
                              hipStream_t stream) {
    const float* x  = (const float*)d_in[0];
    const float* Wq = (const float*)d_in[1];
    const float* Wk = (const float*)d_in[2];
    const float* Wv = (const float*)d_in[3];
    float* out = (float*)d_out;
    __hip_bfloat16* ws = (__hip_bfloat16*)d_ws;

    __hip_bfloat16* xb = (__hip_bfloat16*)d_out;   // overwritten by attn later

    hipLaunchKernelGGL(xcast_kernel, dim3((BATCH * SEQ * EMB) / (256 * 8)), dim3(256),
                       0, stream, x, xb);
    hipLaunchKernelGGL(wt_kernel, dim3(16, 48), dim3(256), 0, stream,
                       Wq, Wk, Wv, ws + WT_OFF);
    hipLaunchKernelGGL(qkv_proj_kernel, dim3(24, 64), dim3(256), 0, stream,
                       xb, ws + WT_OFF, ws);
    hipLaunchKernelGGL(attn_kernel, dim3(1024), dim3(256), 0, stream, ws, out);
}

// Round 8
// 170.573 us; speedup vs baseline: 1.5339x; 1.0717x over previous
//
#include <hip/hip_runtime.h>
#include <hip/hip_bf16.h>

#define BATCH 4
#define SEQ   2048
#define EMB   1024
#define NH    16
#define HD    64

// workspace bf16-element offsets (total 28,311,552 elems = 56.6 MB)
#define Q_OFF  ((size_t)0)           // q  [B][H][T][D]  (0.125*log2e folded into Wq)
#define K_OFF  ((size_t)8388608)     // k  [B][H][T][D]
#define V_OFF  ((size_t)16777216)    // vT [B][H][D][T]
#define WT_OFF ((size_t)25165824)    // Wt [3072][1024] = [mh*64+d][e]

typedef __attribute__((ext_vector_type(8))) short short8;   // 8 bf16
typedef __attribute__((ext_vector_type(4))) short short4v;  // 4 bf16 (8B)
typedef __attribute__((ext_vector_type(4))) float f32x4;    // MFMA acc

__device__ __forceinline__ short8 pack8s(float4 a, float4 b, float s) {
    alignas(16) __hip_bfloat16 t[8] = {
        __float2bfloat16(a.x * s), __float2bfloat16(a.y * s),
        __float2bfloat16(a.z * s), __float2bfloat16(a.w * s),
        __float2bfloat16(b.x * s), __float2bfloat16(b.y * s),
        __float2bfloat16(b.z * s), __float2bfloat16(b.w * s)};
    return *reinterpret_cast<const short8*>(t);
}

// async global->LDS, 16B per lane. LDS dest is wave-uniform base + lane*16.
__device__ __forceinline__ void async16(void* lds, const void* g) {
    __builtin_amdgcn_global_load_lds(
        (const __attribute__((address_space(1))) unsigned int*)g,
        (__attribute__((address_space(3))) unsigned int*)lds, 16, 0, 0);
}

// ---------------------------------------------------------------------------
// Kernel A: x fp32 -> bf16 (linear). Output lives in d_out (overwritten later).
// ---------------------------------------------------------------------------
__global__ __launch_bounds__(256)
void xcast_kernel(const float* __restrict__ x, __hip_bfloat16* __restrict__ xb)
{
    const size_t i = ((size_t)blockIdx.x * 256 + threadIdx.x) * 8;
    float4 f0 = ((const float4*)(x + i))[0];
    float4 f1 = ((const float4*)(x + i))[1];
    *(short8*)(xb + i) = pack8s(f0, f1, 1.0f);
}

// ---------------------------------------------------------------------------
// Kernel B: W transpose+cast: W[h][e][d] fp32 -> Wt[mh*64+d][e] bf16.
// Wq rows scaled by 0.125*log2(e): attention softmax runs in log2 domain.
// ---------------------------------------------------------------------------
__global__ __launch_bounds__(256)
void wt_kernel(const float* __restrict__ Wq, const float* __restrict__ Wk,
               const float* __restrict__ Wv, __hip_bfloat16* __restrict__ Wt)
{
    const int et = blockIdx.x;               // 16 e-tiles of 64
    const int mh = blockIdx.y;               // 48
    const int m = mh >> 4, h = mh & 15;
    const float* W = ((m == 0) ? Wq : (m == 1) ? Wk : Wv) + (size_t)h * (EMB * HD);
    const float scale = (m == 0) ? 0.18033688011112042f : 1.0f;  // 0.125*log2(e)

    __shared__ __hip_bfloat16 T[64][72];     // [d][e-local]
    const int tid = threadIdx.x;
    const int r   = tid >> 2;                // 0..63
    const int seg = (tid & 3) * 16;

    {
        const float* src = W + (size_t)(et * 64 + r) * HD + seg;
        float4 f0 = ((const float4*)src)[0];
        float4 f1 = ((const float4*)src)[1];
        float4 f2 = ((const float4*)src)[2];
        float4 f3 = ((const float4*)src)[3];
        const float v[16] = {f0.x,f0.y,f0.z,f0.w, f1.x,f1.y,f1.z,f1.w,
                             f2.x,f2.y,f2.z,f2.w, f3.x,f3.y,f3.z,f3.w};
        #pragma unroll
        for (int j = 0; j < 16; ++j) T[seg + j][r] = __float2bfloat16(v[j] * scale);
    }
    __syncthreads();
    __hip_bfloat16* dst = Wt + ((size_t)mh * HD + r) * EMB + et * 64 + seg;
    *(short8*)dst       = *(const short8*)&T[r][seg];
    *(short8*)(dst + 8) = *(const short8*)&T[r][seg + 8];
}

// ---------------------------------------------------------------------------
// Kernel 1: QKV projection as bf16 GEMM (m97 structure) — unchanged.
// ---------------------------------------------------------------------------
__global__ __launch_bounds__(256)
void qkv_proj_kernel(const __hip_bfloat16* __restrict__ xb,   // [8192][1024]
                     const __hip_bfloat16* __restrict__ Wt,   // [3072][1024]
                     __hip_bfloat16* __restrict__ qkv)
{
    const int nt = blockIdx.x;               // 0..23 col tiles (2 heads each)
    const int rt = blockIdx.y;               // 0..63 row tiles
    const int row0 = rt * 128;
    const int n0   = nt * 128;

    __shared__ __hip_bfloat16 lds[17408];
    __hip_bfloat16* As = lds;                // [128][64] swizzled, row=128B
    __hip_bfloat16* Bs = lds + 8192;         // [128][64] swizzled

    const int tid  = threadIdx.x;
    const int wave = tid >> 6;
    const int lane = tid & 63;
    const int lr   = lane & 15;
    const int lg   = lane >> 4;

    const int srow  = lane >> 3;
    const int sslot = (lane & 7) ^ srow;
    const char* aSrc = (const char*)xb + (size_t)(row0 + wave * 32 + srow) * 2048 + sslot * 16;
    const char* bSrc = (const char*)Wt + (size_t)(n0   + wave * 32 + srow) * 2048 + sslot * 16;
    char* aDst = (char*)As + (size_t)(wave * 32) * 128;
    char* bDst = (char*)Bs + (size_t)(wave * 32) * 128;

    f32x4 acc[2][8] = {};

    for (int k0 = 0; k0 < EMB; k0 += 64) {
        __syncthreads();
        #pragma unroll
        for (int i = 0; i < 4; ++i) {
            async16(aDst + i * 1024, aSrc + (size_t)i * 16384 + k0 * 2);
            async16(bDst + i * 1024, bSrc + (size_t)i * 16384 + k0 * 2);
        }
        __syncthreads();

        #pragma unroll
        for (int half = 0; half < 2; ++half) {
            const int cg = half * 4 + lg;
            const int r0a = wave * 32 + lr;
            const int r1a = wave * 32 + 16 + lr;
            short8 a0 = *(const short8*)((char*)As + r0a * 128 + ((cg ^ (r0a & 7)) * 16));
            short8 a1 = *(const short8*)((char*)As + r1a * 128 + ((cg ^ (r1a & 7)) * 16));
            #pragma unroll
            for (int ct = 0; ct < 8; ++ct) {
                const int rb = ct * 16 + lr;
                short8 bf = *(const short8*)((char*)Bs + rb * 128 + ((cg ^ (rb & 7)) * 16));
                acc[0][ct] = __builtin_amdgcn_mfma_f32_16x16x32_bf16(a0, bf, acc[0][ct], 0, 0, 0);
                acc[1][ct] = __builtin_amdgcn_mfma_f32_16x16x32_bf16(a1, bf, acc[1][ct], 0, 0, 0);
            }
        }
    }

    const int m   = n0 >> 10;                 // 0,1,2
    const int b   = row0 >> 11;
    const int tl0 = (row0 & (SEQ - 1)) + wave * 32;
    if (m < 2) {
        __hip_bfloat16* outp = qkv + ((m == 0) ? Q_OFF : K_OFF)
                             + (size_t)b * NH * SEQ * HD;
        #pragma unroll
        for (int rsub = 0; rsub < 2; ++rsub)
            #pragma unroll
            for (int ct = 0; ct < 8; ++ct) {
                const int h = (2 * nt + (ct >> 2)) & 15;
                const int d = (ct & 3) * 16 + lr;
                #pragma unroll
                for (int i = 0; i < 4; ++i) {
                    const int trow = tl0 + rsub * 16 + lg * 4 + i;
                    outp[((size_t)h * SEQ + trow) * HD + d] = __float2bfloat16(acc[rsub][ct][i]);
                }
            }
    } else {
        __hip_bfloat16 (*Ts)[136] = (__hip_bfloat16(*)[136])lds;
        __syncthreads();
        #pragma unroll
        for (int rsub = 0; rsub < 2; ++rsub)
            #pragma unroll
            for (int ct = 0; ct < 8; ++ct)
                #pragma unroll
                for (int i = 0; i < 4; ++i)
                    Ts[ct * 16 + lr][wave * 32 + rsub * 16 + lg * 4 + i] =
                        __float2bfloat16(acc[rsub][ct][i]);
        __syncthreads();
        const int c    = tid >> 1;
        const int tseg = (tid & 1) * 64;
        const int hv   = (2 * nt + (c >> 6)) & 15;
        const int dv   = c & 63;
        __hip_bfloat16* dst = qkv + V_OFF + ((size_t)b * NH + hv) * (HD * SEQ)
                            + (size_t)dv * SEQ + (row0 & (SEQ - 1)) + tseg;
        #pragma unroll
        for (int q = 0; q < 8; ++q)
            *(short8*)(dst + q * 8) = *(const short8*)&Ts[c][tseg + q * 8];
    }
}

// ---------------------------------------------------------------------------
// Kernel 2: causal flash attention, swapped-operand (S^T / O^T), r5 structure
// with KVBLK=128: paired q-tiles (p,15-p) -> uniform 17 kv-tiles per block.
// dbuf global_load_lds staging (src pre-swizzle), 1 barrier/tile, setprio.
// LDS 80KB -> 2 blocks/CU.  K rows 128B (8-slot XOR), V/P rows 256B (16-slot).
// ---------------------------------------------------------------------------
__global__ __launch_bounds__(256)
void attn_kernel(const __hip_bfloat16* __restrict__ ws, float* __restrict__ out)
{
    const int bid     = blockIdx.x;                 // 512
    const int logical = (bid & 7) * 64 + (bid >> 3);
    const int p  = logical & 7;
    const int bh = logical >> 3;
    const int h  = bh & 15;
    const int b  = bh >> 4;

    const __hip_bfloat16* qp = ws + Q_OFF + (size_t)bh * (SEQ * HD);
    const __hip_bfloat16* kp = ws + K_OFF + (size_t)bh * (SEQ * HD);
    const __hip_bfloat16* vt = ws + V_OFF + (size_t)bh * (HD * SEQ);  // [d][t]

    __shared__ __align__(16) __hip_bfloat16 Ksb[2][8192];   // [buf][128 key][64 d]
    __shared__ __align__(16) __hip_bfloat16 Vsb[2][8192];   // [buf][64 d][128 key]
    __shared__ __align__(16) __hip_bfloat16 Psb[4][2048];   // per-wave [16 q][128 key]

    const int tid  = threadIdx.x;
    const int wave = tid >> 6;
    const int lane = tid & 63;
    const int lr   = lane & 15;
    const int lg   = lane >> 4;
    const int l7   = lr & 7;

    const int sK = (lane & 7) ^ (lane >> 3);        // K source pre-swizzle slot

    float* op = out + (size_t)b * SEQ * (NH * HD) + (size_t)h * HD;

    for (int seg = 0; seg < 2; ++seg) {
        const int qt    = seg ? (15 - p) : p;
        const int qbase = qt * 128;
        const int ktmax = qt;                       // kv-tiles of 128: 0..qt

        // Q fragments (B-operand layout; 0.125*log2e folded in at projection)
        short8 qf[2][2];
        #pragma unroll
        for (int rsub = 0; rsub < 2; ++rsub) {
            const __hip_bfloat16* src =
                qp + (size_t)(qbase + wave * 32 + rsub * 16 + lr) * HD + lg * 8;
            qf[rsub][0] = *(const short8*)src;
            qf[rsub][1] = *(const short8*)(src + 32);
        }

        float m_run[2] = {-1e30f, -1e30f};
        float l_run[2] = {0.f, 0.f};
        f32x4 o_acc[2][4] = {};

        // stage one 128-key kv-tile: each wave 4 K-issues (32 rows) + 4 V-issues (16 d)
        auto stage = [&](int buf, int kbase) {
            #pragma unroll
            for (int j = 0; j < 4; ++j) {
                const int rk = wave * 32 + j * 8;   // K tile-local row base
                async16((char*)Ksb[buf] + rk * 128,
                        (const char*)(kp + (size_t)(kbase + rk + (lane >> 3)) * HD) + sK * 16);
                const int rv = wave * 16 + j * 4;   // V tile-local d-row base
                const int sV = (lane & 15) ^ ((j * 4 + (lane >> 4)) & 15);
                async16((char*)Vsb[buf] + rv * 256,
                        (const char*)(vt + (size_t)(rv + (lane >> 4)) * SEQ + kbase) + sV * 16);
            }
        };

        stage(0, 0);
        __syncthreads();   // drains async: tile 0 resident

        for (int kt = 0; kt <= ktmax; ++kt) {
            const int cur = kt & 1;
            if (kt < ktmax) stage(cur ^ 1, (kt + 1) * 128);   // T14: issue early

            // S^T = K . Q^T : s[rsub][ct][i] = S[key=ct*16+lg*4+i][qrow(lr)]
            f32x4 s[2][8];
            __builtin_amdgcn_s_setprio(1);
            #pragma unroll
            for (int ct = 0; ct < 8; ++ct) {
                const char* kb = (const char*)Ksb[cur] + (ct * 16 + lr) * 128;
                short8 kf0 = *(const short8*)(kb + ((lg      ^ l7) << 4));
                short8 kf1 = *(const short8*)(kb + (((lg + 4) ^ l7) << 4));
                #pragma unroll
                for (int rsub = 0; rsub < 2; ++rsub) {
                    f32x4 z = {};
                    z           = __builtin_amdgcn_mfma_f32_16x16x32_bf16(kf0, qf[rsub][0], z, 0, 0, 0);
                    s[rsub][ct] = __builtin_amdgcn_mfma_f32_16x16x32_bf16(kf1, qf[rsub][1], z, 0, 0, 0);
                }
            }
            __builtin_amdgcn_s_setprio(0);

            if (kt == qt) {   // causal mask: only the diagonal tile
                const int kbase = kt * 128;
                #pragma unroll
                for (int rsub = 0; rsub < 2; ++rsub) {
                    const int qrow = qbase + wave * 32 + rsub * 16 + lr;
                    #pragma unroll
                    for (int ct = 0; ct < 8; ++ct)
                        #pragma unroll
                        for (int i = 0; i < 4; ++i) {
                            const int key = kbase + ct * 16 + lg * 4 + i;
                            s[rsub][ct][i] = (key > qrow) ? -1e30f : s[rsub][ct][i];
                        }
                }
            }

            // softmax (log2 domain, defer-max); P routed per-rsub through Psb
            short8 pf[2][4];
            #pragma unroll
            for (int rsub = 0; rsub < 2; ++rsub) {
                float mx01 = fmaxf(fmaxf(fmaxf(s[rsub][0][0], s[rsub][0][1]), fmaxf(s[rsub][0][2], s[rsub][0][3])),
                                   fmaxf(fmaxf(s[rsub][1][0], s[rsub][1][1]), fmaxf(s[rsub][1][2], s[rsub][1][3])));
                float mx23 = fmaxf(fmaxf(fmaxf(s[rsub][2][0], s[rsub][2][1]), fmaxf(s[rsub][2][2], s[rsub][2][3])),
                                   fmaxf(fmaxf(s[rsub][3][0], s[rsub][3][1]), fmaxf(s[rsub][3][2], s[rsub][3][3])));
                float mx45 = fmaxf(fmaxf(fmaxf(s[rsub][4][0], s[rsub][4][1]), fmaxf(s[rsub][4][2], s[rsub][4][3])),
                                   fmaxf(fmaxf(s[rsub][5][0], s[rsub][5][1]), fmaxf(s[rsub][5][2], s[rsub][5][3])));
                float mx67 = fmaxf(fmaxf(fmaxf(s[rsub][6][0], s[rsub][6][1]), fmaxf(s[rsub][6][2], s[rsub][6][3])),
                                   fmaxf(fmaxf(s[rsub][7][0], s[rsub][7][1]), fmaxf(s[rsub][7][2], s[rsub][7][3])));
                float pmax = fmaxf(fmaxf(mx01, mx23), fmaxf(mx45, mx67));
                pmax = fmaxf(pmax, __shfl_xor(pmax, 16, 64));
                pmax = fmaxf(pmax, __shfl_xor(pmax, 32, 64));

                // T13 defer-max (THR=8 -> P <= 256)
                if (__any(pmax > m_run[rsub] + 8.0f)) {
                    const float mnew = fmaxf(m_run[rsub], pmax);
                    const float corr = __builtin_amdgcn_exp2f(m_run[rsub] - mnew);
                    l_run[rsub] *= corr;
                    #pragma unroll
                    for (int ct = 0; ct < 4; ++ct)
                        #pragma unroll
                        for (int i = 0; i < 4; ++i)
                            o_acc[rsub][ct][i] *= corr;
                    m_run[rsub] = mnew;
                }

                const float mcur = m_run[rsub];
                float rs0 = 0.f, rs1 = 0.f;
                #pragma unroll
                for (int ct = 0; ct < 8; ++ct) {
                    const float p0 = __builtin_amdgcn_exp2f(s[rsub][ct][0] - mcur);
                    const float p1 = __builtin_amdgcn_exp2f(s[rsub][ct][1] - mcur);
                    const float p2 = __builtin_amdgcn_exp2f(s[rsub][ct][2] - mcur);
                    const float p3 = __builtin_amdgcn_exp2f(s[rsub][ct][3] - mcur);
                    rs0 += p0 + p1;
                    rs1 += p2 + p3;
                    alignas(8) __hip_bfloat16 t[4] = {
                        __float2bfloat16(p0), __float2bfloat16(p1),
                        __float2bfloat16(p2), __float2bfloat16(p3)};
                    // element slot = 2ct + (lg>>1); physical slot = elem ^ lr (16 slots)
                    *(short4v*)((char*)Psb[wave] + lr * 256
                        + (((2 * ct + (lg >> 1)) ^ lr) << 4) + 8 * (lg & 1)) = *(const short4v*)t;
                }
                float rs = rs0 + rs1;
                rs += __shfl_xor(rs, 16, 64);
                rs += __shfl_xor(rs, 32, 64);
                l_run[rsub] += rs;

                // pf[q] = P[keys q*32+lg*8..+7][row lr]  (elem slot 4q+lg, ^lr)
                const char* pb = (const char*)Psb[wave] + lr * 256;
                #pragma unroll
                for (int q = 0; q < 4; ++q)
                    pf[rsub][q] = *(const short8*)(pb + (((4 * q + lg) ^ lr) << 4));
            }

            // O^T += V^T . P : vf shared across rsub
            __builtin_amdgcn_s_setprio(1);
            #pragma unroll
            for (int ct = 0; ct < 4; ++ct) {
                const char* vb = (const char*)Vsb[cur] + (ct * 16 + lr) * 256;
                #pragma unroll
                for (int q = 0; q < 4; ++q) {
                    short8 vf = *(const short8*)(vb + (((4 * q + lg) ^ lr) << 4));
                    o_acc[0][ct] = __builtin_amdgcn_mfma_f32_16x16x32_bf16(vf, pf[0][q], o_acc[0][ct], 0, 0, 0);
                    o_acc[1][ct] = __builtin_amdgcn_mfma_f32_16x16x32_bf16(vf, pf[1][q], o_acc[1][ct], 0, 0, 0);
                }
            }
            __builtin_amdgcn_s_setprio(0);

            __syncthreads();   // single barrier: drains async stage, fences dbuf swap
        }

        // epilogue: O^T -> out[b][t][h*64+d]; qrow lane-local -> float4 stores
        #pragma unroll
        for (int rsub = 0; rsub < 2; ++rsub) {
            const float inv  = 1.0f / l_run[rsub];
            const int   trow = qbase + wave * 32 + rsub * 16 + lr;
            #pragma unroll
            for (int ct = 0; ct < 4; ++ct) {
                float4 o;
                o.x = o_acc[rsub][ct][0] * inv;
                o.y = o_acc[rsub][ct][1] * inv;
                o.z = o_acc[rsub][ct][2] * inv;
                o.w = o_acc[rsub][ct][3] * inv;
                *(float4*)&op[(size_t)trow * (NH * HD) + ct * 16 + lg * 4] = o;
            }
        }
    }
}

extern "C" void kernel_launch(void* const* d_in, const int* in_sizes, int n_in,
                              void* d_out, int out_size, void* d_ws, size_t ws_size,
                              hipStream_t stream) {
    const float* x  = (const float*)d_in[0];
    const float* Wq = (const float*)d_in[1];
    const float* Wk = (const float*)d_in[2];
    const float* Wv = (const float*)d_in[3];
    float* out = (float*)d_out;
    __hip_bfloat16* ws = (__hip_bfloat16*)d_ws;

    __hip_bfloat16* xb = (__hip_bfloat16*)d_out;   // overwritten by attn later

    hipLaunchKernelGGL(xcast_kernel, dim3((BATCH * SEQ * EMB) / (256 * 8)), dim3(256),
                       0, stream, x, xb);
    hipLaunchKernelGGL(wt_kernel, dim3(16, 48), dim3(256), 0, stream,
                       Wq, Wk, Wv, ws + WT_OFF);
    hipLaunchKernelGGL(qkv_proj_kernel, dim3(24, 64), dim3(256), 0, stream,
                       xb, ws + WT_OFF, ws);
    hipLaunchKernelGGL(attn_kernel, dim3(512), dim3(256), 0, stream, ws, out);
}

// Round 9
// 155.551 us; speedup vs baseline: 1.6821x; 1.0966x over previous
//
#include <hip/hip_runtime.h>
#include <hip/hip_bf16.h>

#define BATCH 4
#define SEQ   2048
#define EMB   1024
#define NH    16
#define HD    64

// workspace bf16-element offsets (total 28,311,552 elems = 56.6 MB)
#define Q_OFF  ((size_t)0)           // q  [B][H][T][D]  (0.125*log2e folded into Wq)
#define K_OFF  ((size_t)8388608)     // k  [B][H][T][D]
#define V_OFF  ((size_t)16777216)    // vT [B][H][D][T]
#define WT_OFF ((size_t)25165824)    // Wt [3072][1024] = [mh*64+d][e]

typedef __attribute__((ext_vector_type(8))) short short8;   // 8 bf16
typedef __attribute__((ext_vector_type(4))) short short4v;  // 4 bf16 (8B)
typedef __attribute__((ext_vector_type(4))) float f32x4;    // MFMA acc

__device__ __forceinline__ short8 pack8s(float4 a, float4 b, float s) {
    alignas(16) __hip_bfloat16 t[8] = {
        __float2bfloat16(a.x * s), __float2bfloat16(a.y * s),
        __float2bfloat16(a.z * s), __float2bfloat16(a.w * s),
        __float2bfloat16(b.x * s), __float2bfloat16(b.y * s),
        __float2bfloat16(b.z * s), __float2bfloat16(b.w * s)};
    return *reinterpret_cast<const short8*>(t);
}

// async global->LDS, 16B per lane. LDS dest is wave-uniform base + lane*16.
__device__ __forceinline__ void async16(void* lds, const void* g) {
    __builtin_amdgcn_global_load_lds(
        (const __attribute__((address_space(1))) unsigned int*)g,
        (__attribute__((address_space(3))) unsigned int*)lds, 16, 0, 0);
}

// ---------------------------------------------------------------------------
// Kernel A: x fp32 -> bf16 (linear). Output lives in d_out (overwritten later).
// ---------------------------------------------------------------------------
__global__ __launch_bounds__(256)
void xcast_kernel(const float* __restrict__ x, __hip_bfloat16* __restrict__ xb)
{
    const size_t i = ((size_t)blockIdx.x * 256 + threadIdx.x) * 8;
    float4 f0 = ((const float4*)(x + i))[0];
    float4 f1 = ((const float4*)(x + i))[1];
    *(short8*)(xb + i) = pack8s(f0, f1, 1.0f);
}

// ---------------------------------------------------------------------------
// Kernel B: W transpose+cast: W[h][e][d] fp32 -> Wt[mh*64+d][e] bf16.
// Wq rows scaled by 0.125*log2(e): attention softmax runs in log2 domain.
// ---------------------------------------------------------------------------
__global__ __launch_bounds__(256)
void wt_kernel(const float* __restrict__ Wq, const float* __restrict__ Wk,
               const float* __restrict__ Wv, __hip_bfloat16* __restrict__ Wt)
{
    const int et = blockIdx.x;               // 16 e-tiles of 64
    const int mh = blockIdx.y;               // 48
    const int m = mh >> 4, h = mh & 15;
    const float* W = ((m == 0) ? Wq : (m == 1) ? Wk : Wv) + (size_t)h * (EMB * HD);
    const float scale = (m == 0) ? 0.18033688011112042f : 1.0f;  // 0.125*log2(e)

    __shared__ __hip_bfloat16 T[64][72];     // [d][e-local]
    const int tid = threadIdx.x;
    const int r   = tid >> 2;                // 0..63
    const int seg = (tid & 3) * 16;

    {
        const float* src = W + (size_t)(et * 64 + r) * HD + seg;
        float4 f0 = ((const float4*)src)[0];
        float4 f1 = ((const float4*)src)[1];
        float4 f2 = ((const float4*)src)[2];
        float4 f3 = ((const float4*)src)[3];
        const float v[16] = {f0.x,f0.y,f0.z,f0.w, f1.x,f1.y,f1.z,f1.w,
                             f2.x,f2.y,f2.z,f2.w, f3.x,f3.y,f3.z,f3.w};
        #pragma unroll
        for (int j = 0; j < 16; ++j) T[seg + j][r] = __float2bfloat16(v[j] * scale);
    }
    __syncthreads();
    __hip_bfloat16* dst = Wt + ((size_t)mh * HD + r) * EMB + et * 64 + seg;
    *(short8*)dst       = *(const short8*)&T[r][seg];
    *(short8*)(dst + 8) = *(const short8*)&T[r][seg + 8];
}

// ---------------------------------------------------------------------------
// Kernel 1: QKV projection as bf16 GEMM (m97 structure) — unchanged.
// ---------------------------------------------------------------------------
__global__ __launch_bounds__(256)
void qkv_proj_kernel(const __hip_bfloat16* __restrict__ xb,   // [8192][1024]
                     const __hip_bfloat16* __restrict__ Wt,   // [3072][1024]
                     __hip_bfloat16* __restrict__ qkv)
{
    const int nt = blockIdx.x;               // 0..23 col tiles (2 heads each)
    const int rt = blockIdx.y;               // 0..63 row tiles
    const int row0 = rt * 128;
    const int n0   = nt * 128;

    __shared__ __hip_bfloat16 lds[17408];
    __hip_bfloat16* As = lds;                // [128][64] swizzled, row=128B
    __hip_bfloat16* Bs = lds + 8192;         // [128][64] swizzled

    const int tid  = threadIdx.x;
    const int wave = tid >> 6;
    const int lane = tid & 63;
    const int lr   = lane & 15;
    const int lg   = lane >> 4;

    const int srow  = lane >> 3;
    const int sslot = (lane & 7) ^ srow;
    const char* aSrc = (const char*)xb + (size_t)(row0 + wave * 32 + srow) * 2048 + sslot * 16;
    const char* bSrc = (const char*)Wt + (size_t)(n0   + wave * 32 + srow) * 2048 + sslot * 16;
    char* aDst = (char*)As + (size_t)(wave * 32) * 128;
    char* bDst = (char*)Bs + (size_t)(wave * 32) * 128;

    f32x4 acc[2][8] = {};

    for (int k0 = 0; k0 < EMB; k0 += 64) {
        __syncthreads();
        #pragma unroll
        for (int i = 0; i < 4; ++i) {
            async16(aDst + i * 1024, aSrc + (size_t)i * 16384 + k0 * 2);
            async16(bDst + i * 1024, bSrc + (size_t)i * 16384 + k0 * 2);
        }
        __syncthreads();

        #pragma unroll
        for (int half = 0; half < 2; ++half) {
            const int cg = half * 4 + lg;
            const int r0a = wave * 32 + lr;
            const int r1a = wave * 32 + 16 + lr;
            short8 a0 = *(const short8*)((char*)As + r0a * 128 + ((cg ^ (r0a & 7)) * 16));
            short8 a1 = *(const short8*)((char*)As + r1a * 128 + ((cg ^ (r1a & 7)) * 16));
            #pragma unroll
            for (int ct = 0; ct < 8; ++ct) {
                const int rb = ct * 16 + lr;
                short8 bf = *(const short8*)((char*)Bs + rb * 128 + ((cg ^ (rb & 7)) * 16));
                acc[0][ct] = __builtin_amdgcn_mfma_f32_16x16x32_bf16(a0, bf, acc[0][ct], 0, 0, 0);
                acc[1][ct] = __builtin_amdgcn_mfma_f32_16x16x32_bf16(a1, bf, acc[1][ct], 0, 0, 0);
            }
        }
    }

    const int m   = n0 >> 10;                 // 0,1,2
    const int b   = row0 >> 11;
    const int tl0 = (row0 & (SEQ - 1)) + wave * 32;
    if (m < 2) {
        __hip_bfloat16* outp = qkv + ((m == 0) ? Q_OFF : K_OFF)
                             + (size_t)b * NH * SEQ * HD;
        #pragma unroll
        for (int rsub = 0; rsub < 2; ++rsub)
            #pragma unroll
            for (int ct = 0; ct < 8; ++ct) {
                const int h = (2 * nt + (ct >> 2)) & 15;
                const int d = (ct & 3) * 16 + lr;
                #pragma unroll
                for (int i = 0; i < 4; ++i) {
                    const int trow = tl0 + rsub * 16 + lg * 4 + i;
                    outp[((size_t)h * SEQ + trow) * HD + d] = __float2bfloat16(acc[rsub][ct][i]);
                }
            }
    } else {
        __hip_bfloat16 (*Ts)[136] = (__hip_bfloat16(*)[136])lds;
        __syncthreads();
        #pragma unroll
        for (int rsub = 0; rsub < 2; ++rsub)
            #pragma unroll
            for (int ct = 0; ct < 8; ++ct)
                #pragma unroll
                for (int i = 0; i < 4; ++i)
                    Ts[ct * 16 + lr][wave * 32 + rsub * 16 + lg * 4 + i] =
                        __float2bfloat16(acc[rsub][ct][i]);
        __syncthreads();
        const int c    = tid >> 1;
        const int tseg = (tid & 1) * 64;
        const int hv   = (2 * nt + (c >> 6)) & 15;
        const int dv   = c & 63;
        __hip_bfloat16* dst = qkv + V_OFF + ((size_t)b * NH + hv) * (HD * SEQ)
                            + (size_t)dv * SEQ + (row0 & (SEQ - 1)) + tseg;
        #pragma unroll
        for (int q = 0; q < 8; ++q)
            *(short8*)(dst + q * 8) = *(const short8*)&Ts[c][tseg + q * 8];
    }
}

// ---------------------------------------------------------------------------
// Kernel 2: causal flash attention — r5 per-wave shape (KVBLK=64, 4 waves x
// 32 q-rows, dbuf gload_lds staging, T2 swizzle, 1 barrier/tile) with:
//   * LPT dispatch: 1024 blocks, qt = 15 - (bid>>6)  (monsters first,
//     1-tile blocks last -> tiny drain tail); bh = bid&63 so bid%8 = bh%8
//     pins each (b,h)'s K/V to one XCD L2 across its 16 q-blocks.
//   * P buffer shared across rsub (same-wave DS ops are in-order) -> 40KB
//     LDS -> 4 blocks/CU (16 waves/CU).
// ---------------------------------------------------------------------------
__global__ __launch_bounds__(256)
void attn_kernel(const __hip_bfloat16* __restrict__ ws, float* __restrict__ out)
{
    const int bid = blockIdx.x;              // 1024
    const int qt  = 15 - (bid >> 6);         // LPT: longest first
    const int bh  = bid & 63;
    const int h   = bh & 15;
    const int b   = bh >> 4;
    const int qbase = qt * 128;
    const int ktmax = 2 * qt + 1;

    const __hip_bfloat16* qp = ws + Q_OFF + (size_t)bh * (SEQ * HD);
    const __hip_bfloat16* kp = ws + K_OFF + (size_t)bh * (SEQ * HD);
    const __hip_bfloat16* vt = ws + V_OFF + (size_t)bh * (HD * SEQ);  // [d][t]

    // swizzled tiles: element slot s of row r at byte r*128 + ((s^(r&7))<<4)
    __shared__ __align__(16) __hip_bfloat16 Ksb[2][4096];   // [buf][64 key][64 d]
    __shared__ __align__(16) __hip_bfloat16 Vsb[2][4096];   // [buf][64 d][64 key]
    __shared__ __align__(16) __hip_bfloat16 Psb[4][1024];   // per-wave P (rsub-shared)

    const int tid  = threadIdx.x;
    const int wave = tid >> 6;
    const int lane = tid & 63;
    const int lr   = lane & 15;
    const int lg   = lane >> 4;
    const int l7   = lr & 7;

    const int srow8 = lane >> 3;            // 0..7 within an 8-row issue
    const int sslot = (lane & 7) ^ srow8;   // source pre-swizzle slot

    // Q fragments (B-operand layout; 0.125*log2e folded in at projection)
    short8 qf[2][2];
    #pragma unroll
    for (int rsub = 0; rsub < 2; ++rsub) {
        const __hip_bfloat16* src =
            qp + (size_t)(qbase + wave * 32 + rsub * 16 + lr) * HD + lg * 8;
        qf[rsub][0] = *(const short8*)src;
        qf[rsub][1] = *(const short8*)(src + 32);
    }

    float m_run[2] = {-1e30f, -1e30f};
    float l_run[2] = {0.f, 0.f};
    f32x4 o_acc[2][4] = {};

    // async stage of one kv-tile into buf (each wave: 16 K rows + 16 V rows)
    auto stage = [&](int buf, int kbase) {
        #pragma unroll
        for (int j = 0; j < 2; ++j) {
            const int r0 = wave * 16 + j * 8;   // tile-local row base (mult of 8)
            async16((char*)Ksb[buf] + r0 * 128,
                    (const char*)(kp + (size_t)(kbase + r0 + srow8) * HD) + sslot * 16);
            async16((char*)Vsb[buf] + r0 * 128,
                    (const char*)(vt + (size_t)(r0 + srow8) * SEQ + kbase) + sslot * 16);
        }
    };

    stage(0, 0);
    __syncthreads();   // drains async: tile 0 resident

    for (int kt = 0; kt <= ktmax; ++kt) {
        const int cur = kt & 1;
        if (kt < ktmax) stage(cur ^ 1, (kt + 1) * 64);   // T14: issue early

        // S^T = K . Q^T : s[rsub][ct][i] = S[key=ct*16+lg*4+i][qrow(lr)]
        f32x4 s[2][4];
        __builtin_amdgcn_s_setprio(1);
        #pragma unroll
        for (int ct = 0; ct < 4; ++ct) {
            const char* kb = (const char*)Ksb[cur] + (ct * 16 + lr) * 128;
            short8 kf0 = *(const short8*)(kb + ((lg      ^ l7) << 4));
            short8 kf1 = *(const short8*)(kb + (((lg + 4) ^ l7) << 4));
            #pragma unroll
            for (int rsub = 0; rsub < 2; ++rsub) {
                f32x4 z = {};
                z           = __builtin_amdgcn_mfma_f32_16x16x32_bf16(kf0, qf[rsub][0], z, 0, 0, 0);
                s[rsub][ct] = __builtin_amdgcn_mfma_f32_16x16x32_bf16(kf1, qf[rsub][1], z, 0, 0, 0);
            }
        }
        __builtin_amdgcn_s_setprio(0);

        const int kbase = kt * 64;
        if (kt >= 2 * qt) {   // causal mask (diagonal tiles only)
            #pragma unroll
            for (int rsub = 0; rsub < 2; ++rsub) {
                const int qrow = qbase + wave * 32 + rsub * 16 + lr;
                #pragma unroll
                for (int ct = 0; ct < 4; ++ct)
                    #pragma unroll
                    for (int i = 0; i < 4; ++i) {
                        const int key = kbase + ct * 16 + lg * 4 + i;
                        s[rsub][ct][i] = (key > qrow) ? -1e30f : s[rsub][ct][i];
                    }
            }
        }

        // softmax (log2 domain, defer-max); P buffer shared across rsub
        short8 pf[2][2];
        #pragma unroll
        for (int rsub = 0; rsub < 2; ++rsub) {
            float pmax = fmaxf(
                fmaxf(fmaxf(fmaxf(s[rsub][0][0], s[rsub][0][1]), fmaxf(s[rsub][0][2], s[rsub][0][3])),
                      fmaxf(fmaxf(s[rsub][1][0], s[rsub][1][1]), fmaxf(s[rsub][1][2], s[rsub][1][3]))),
                fmaxf(fmaxf(fmaxf(s[rsub][2][0], s[rsub][2][1]), fmaxf(s[rsub][2][2], s[rsub][2][3])),
                      fmaxf(fmaxf(s[rsub][3][0], s[rsub][3][1]), fmaxf(s[rsub][3][2], s[rsub][3][3]))));
            pmax = fmaxf(pmax, __shfl_xor(pmax, 16, 64));
            pmax = fmaxf(pmax, __shfl_xor(pmax, 32, 64));

            // T13 defer-max (log2 domain, THR=8 -> P <= 256)
            if (__any(pmax > m_run[rsub] + 8.0f)) {
                const float mnew = fmaxf(m_run[rsub], pmax);
                const float corr = __builtin_amdgcn_exp2f(m_run[rsub] - mnew);
                l_run[rsub] *= corr;
                #pragma unroll
                for (int ct = 0; ct < 4; ++ct)
                    #pragma unroll
                    for (int i = 0; i < 4; ++i)
                        o_acc[rsub][ct][i] *= corr;
                m_run[rsub] = mnew;
            }

            const float mcur = m_run[rsub];
            float rs0 = 0.f, rs1 = 0.f;
            #pragma unroll
            for (int ct = 0; ct < 4; ++ct) {
                const float p0 = __builtin_amdgcn_exp2f(s[rsub][ct][0] - mcur);
                const float p1 = __builtin_amdgcn_exp2f(s[rsub][ct][1] - mcur);
                const float p2 = __builtin_amdgcn_exp2f(s[rsub][ct][2] - mcur);
                const float p3 = __builtin_amdgcn_exp2f(s[rsub][ct][3] - mcur);
                rs0 += p0 + p1;
                rs1 += p2 + p3;
                alignas(8) __hip_bfloat16 t[4] = {
                    __float2bfloat16(p0), __float2bfloat16(p1),
                    __float2bfloat16(p2), __float2bfloat16(p3)};
                *(short4v*)((char*)Psb[wave] + lr * 128
                    + (((2 * ct + (lg >> 1)) ^ l7) << 4) + 8 * (lg & 1)) = *(const short4v*)t;
            }
            float rs = rs0 + rs1;
            rs += __shfl_xor(rs, 16, 64);
            rs += __shfl_xor(rs, 32, 64);
            l_run[rsub] += rs;

            // read pf before next rsub overwrites (same-wave DS ops in-order)
            const char* pb = (const char*)Psb[wave] + lr * 128;
            pf[rsub][0] = *(const short8*)(pb + ((lg      ^ l7) << 4));
            pf[rsub][1] = *(const short8*)(pb + (((lg + 4) ^ l7) << 4));
        }

        // O^T += V^T . P (vf shared across rsub)
        __builtin_amdgcn_s_setprio(1);
        #pragma unroll
        for (int ct = 0; ct < 4; ++ct) {
            const char* vb = (const char*)Vsb[cur] + (ct * 16 + lr) * 128;
            short8 vf0 = *(const short8*)(vb + ((lg      ^ l7) << 4));
            short8 vf1 = *(const short8*)(vb + (((lg + 4) ^ l7) << 4));
            #pragma unroll
            for (int rsub = 0; rsub < 2; ++rsub) {
                o_acc[rsub][ct] = __builtin_amdgcn_mfma_f32_16x16x32_bf16(vf0, pf[rsub][0], o_acc[rsub][ct], 0, 0, 0);
                o_acc[rsub][ct] = __builtin_amdgcn_mfma_f32_16x16x32_bf16(vf1, pf[rsub][1], o_acc[rsub][ct], 0, 0, 0);
            }
        }
        __builtin_amdgcn_s_setprio(0);

        __syncthreads();   // single barrier: drains async stage, fences dbuf swap
    }

    // epilogue: O^T -> out[b][t][h*64+d]; qrow lane-local -> float4 stores
    float* op = out + (size_t)b * SEQ * (NH * HD) + (size_t)h * HD;
    #pragma unroll
    for (int rsub = 0; rsub < 2; ++rsub) {
        const float inv  = 1.0f / l_run[rsub];
        const int   trow = qbase + wave * 32 + rsub * 16 + lr;
        #pragma unroll
        for (int ct = 0; ct < 4; ++ct) {
            float4 o;
            o.x = o_acc[rsub][ct][0] * inv;
            o.y = o_acc[rsub][ct][1] * inv;
            o.z = o_acc[rsub][ct][2] * inv;
            o.w = o_acc[rsub][ct][3] * inv;
            *(float4*)&op[(size_t)trow * (NH * HD) + ct * 16 + lg * 4] = o;
        }
    }
}

extern "C" void kernel_launch(void* const* d_in, const int* in_sizes, int n_in,
                              void* d_out, int out_size, void* d_ws, size_t ws_size,
                              hipStream_t stream) {
    const float* x  = (const float*)d_in[0];
    const float* Wq = (const float*)d_in[1];
    const float* Wk = (const float*)d_in[2];
    const float* Wv = (const float*)d_in[3];
    float* out = (float*)d_out;
    __hip_bfloat16* ws = (__hip_bfloat16*)d_ws;

    __hip_bfloat16* xb = (__hip_bfloat16*)d_out;   // overwritten by attn later

    hipLaunchKernelGGL(xcast_kernel, dim3((BATCH * SEQ * EMB) / (256 * 8)), dim3(256),
                       0, stream, x, xb);
    hipLaunchKernelGGL(wt_kernel, dim3(16, 48), dim3(256), 0, stream,
                       Wq, Wk, Wv, ws + WT_OFF);
    hipLaunchKernelGGL(qkv_proj_kernel, dim3(24, 64), dim3(256), 0, stream,
                       xb, ws + WT_OFF, ws);
    hipLaunchKernelGGL(attn_kernel, dim3(1024), dim3(256), 0, stream, ws, out);
}